// Round 14
// baseline (85.813 us; speedup 1.0000x reference)
//
#include <hip/hip_runtime.h>

// ReactionTerm v11b: cross-region software pipeline with VGPR-safe staging.
// (R13 resubmit: fixed `SET##1.x` pp-number pasting -> `(SET##1).x`.)
// Model (R12 post-mortem): per region, loads are issued AND consumed inside
// the same barrier pair, so HBM idles during every SUM+WRITE LDS window
// (~2us x 10 regions = the stable 22us gap). R8 proved the barrier-crossing
// concept fails only via VGPR overflow (2x16 float4 regs). R13: 2048-term
// chunks, rates staged as float2 double-buffer (16 VGPRs), issued in region r,
// consumed in region r+1, across relaxed lgkmcnt-only barriers. fp16 buf
// (validated R11/R12): LDS 40KB/block -> 2 blocks/CU at 1024 threads,
// __launch_bounds__(1024,8) pins VGPR<=64.
// Geometry: B=4096, S=1024, N1=4096, N2=16384.

typedef __attribute__((ext_vector_type(4))) _Float16 half4;

#define SWL(k) ((k) ^ (((k) >> 3) & 7))

// LDS-only barrier: orders LDS ops, leaves global loads in flight (R8-proven).
#define LDS_BARRIER()                                          \
    do {                                                       \
        asm volatile("s_waitcnt lgkmcnt(0)" ::: "memory");     \
        __builtin_amdgcn_s_barrier();                          \
    } while (0)

// ---------- setup: 10 blocks, one per 2048-term chunk ------------------------
// chunks 0..1 = first-order halves; chunks 2..9 = second-order eighths.
__global__ __launch_bounds__(1024) void setup_kernel(
    const int* __restrict__ i1p, const int* __restrict__ i2p,
    unsigned short* __restrict__ pos1, unsigned short* __restrict__ pos2,
    unsigned* __restrict__ segpack) {
    __shared__ int h[1024];
    __shared__ int wsum[16];
    const int tid = threadIdx.x;
    const int ch  = blockIdx.x;
    const int* __restrict__ ip = (ch < 2) ? (i1p + ch * 2048)
                                          : (i2p + (ch - 2) * 2048);
    unsigned short* __restrict__ pos = (ch < 2) ? (pos1 + ch * 2048)
                                                : (pos2 + (ch - 2) * 2048);

    h[tid] = 0;
    __syncthreads();
    const int2 t2 = ((const int2*)ip)[tid];
    atomicAdd(&h[t2.x], 1);
    atomicAdd(&h[t2.y], 1);
    __syncthreads();
    const int n = h[tid];

    // 1024-wide exclusive scan: wave shfl butterfly + 16-wave combine (R12).
    const int lane = tid & 63, w = tid >> 6;
    int v = n;
#pragma unroll
    for (int d = 1; d < 64; d <<= 1) {
        int t = __shfl_up(v, d, 64);
        if (lane >= d) v += t;
    }
    if (lane == 63) wsum[w] = v;
    __syncthreads();
    if (tid < 16) {
        int s = wsum[tid];
#pragma unroll
        for (int d = 1; d < 16; d <<= 1) {
            int t = __shfl_up(s, d, 64);
            if (tid >= d) s += t;
        }
        wsum[tid] = s;
    }
    __syncthreads();
    const int start = ((w ? wsum[w - 1] : 0) + v) - n;   // exclusive, < 2048
    segpack[ch * 1024 + tid] = (unsigned)start | ((unsigned)n << 16);
    __syncthreads();
    h[tid] = start;                                      // reuse as cursor
    __syncthreads();
    const int p0 = atomicAdd(&h[t2.x], 1);
    const int p1 = atomicAdd(&h[t2.y], 1);
    unsigned o = (unsigned)(unsigned short)SWL(p0)
               | ((unsigned)(unsigned short)SWL(p1) << 16);
    ((unsigned*)pos)[tid] = o;
}

// ---------- main: 4 rows/block (fp16 buf), 1024 threads, pipelined -----------
__global__ __launch_bounds__(1024, 8) void reaction_gather4p(
    const float* __restrict__ y_in, const float* __restrict__ rate_1,
    const float* __restrict__ rate_2,
    const int* __restrict__ i1r, const int* __restrict__ i2r,
    const unsigned short* __restrict__ pos1, const unsigned short* __restrict__ pos2,
    const unsigned* __restrict__ segpack,
    float* __restrict__ y_out) {
    __shared__ half4 y_s[1024];     //  8 KB: 4 rows fp16
    __shared__ half4 buf[2][2048];  // 32 KB: double-buffered product chunks

    const int tid = threadIdx.x;
    const long b0 = (long)blockIdx.x * 4;
    const float* __restrict__ r1b = rate_1 + b0 * 4096;
    const float* __restrict__ r2b = rate_2 + b0 * 16384;

    float acc[4] = {0.f, 0.f, 0.f, 0.f};
    // Double-buffered rate staging: 8 float2 = 16 VGPRs total.
    float2 qA0, qA1, qA2, qA3, qB0, qB1, qB2, qB3;

    // (SET##r) = row r rates for this thread's 2 terms of the chunk.
#define ISSUE_PH1(SET, C)                                                      \
    SET##0 = ((const float2*)(r1b + (C) * 2048         ))[tid];                \
    SET##1 = ((const float2*)(r1b + (C) * 2048 +  4096))[tid];                 \
    SET##2 = ((const float2*)(r1b + (C) * 2048 +  8192))[tid];                 \
    SET##3 = ((const float2*)(r1b + (C) * 2048 + 12288))[tid];

#define ISSUE_PH2(SET, C)                                                      \
    SET##0 = ((const float2*)(r2b + (C) * 2048         ))[tid];                \
    SET##1 = ((const float2*)(r2b + (C) * 2048 + 16384))[tid];                 \
    SET##2 = ((const float2*)(r2b + (C) * 2048 + 32768))[tid];                 \
    SET##3 = ((const float2*)(r2b + (C) * 2048 + 49152))[tid];

#define WRITE_PH1(P, SET, C)                                                   \
    {                                                                          \
        int2     ia = ((const int2*)(i1r + (C) * 2048))[tid];                  \
        unsigned pp = ((const unsigned*)(pos1 + (C) * 2048))[tid];             \
        half4 ya = y_s[ia.x], yb = y_s[ia.y], pr;                              \
        pr[0] = (_Float16)((float)ya[0] * (SET##0).x);                         \
        pr[1] = (_Float16)((float)ya[1] * (SET##1).x);                         \
        pr[2] = (_Float16)((float)ya[2] * (SET##2).x);                         \
        pr[3] = (_Float16)((float)ya[3] * (SET##3).x);                         \
        buf[P][pp & 0xffffu] = pr;                                             \
        pr[0] = (_Float16)((float)yb[0] * (SET##0).y);                         \
        pr[1] = (_Float16)((float)yb[1] * (SET##1).y);                         \
        pr[2] = (_Float16)((float)yb[2] * (SET##2).y);                         \
        pr[3] = (_Float16)((float)yb[3] * (SET##3).y);                         \
        buf[P][pp >> 16] = pr;                                                 \
    }

#define WRITE_PH2(P, SET, C)                                                   \
    {                                                                          \
        int4     e  = ((const int4*)(i2r + (C) * 4096))[tid];                  \
        unsigned pp = ((const unsigned*)(pos2 + (C) * 2048))[tid];             \
        half4 a0 = y_s[e.x], c0 = y_s[e.y];                                    \
        half4 a1 = y_s[e.z], c1 = y_s[e.w];                                    \
        half4 pr;                                                              \
        pr[0] = (_Float16)((float)a0[0] * (float)c0[0] * (SET##0).x);          \
        pr[1] = (_Float16)((float)a0[1] * (float)c0[1] * (SET##1).x);          \
        pr[2] = (_Float16)((float)a0[2] * (float)c0[2] * (SET##2).x);          \
        pr[3] = (_Float16)((float)a0[3] * (float)c0[3] * (SET##3).x);          \
        buf[P][pp & 0xffffu] = pr;                                             \
        pr[0] = (_Float16)((float)a1[0] * (float)c1[0] * (SET##0).y);          \
        pr[1] = (_Float16)((float)a1[1] * (float)c1[1] * (SET##1).y);          \
        pr[2] = (_Float16)((float)a1[2] * (float)c1[2] * (SET##2).y);          \
        pr[3] = (_Float16)((float)a1[3] * (float)c1[3] * (SET##3).y);          \
        buf[P][pp >> 16] = pr;                                                 \
    }

#define SUM(CH, P)                                                             \
    {                                                                          \
        unsigned sp = segpack[(CH) * 1024 + tid];                              \
        int s = (int)(sp & 0xffffu), n = (int)(sp >> 16);                      \
        for (int k = s; k < s + n; ++k) {                                      \
            half4 v = buf[P][SWL(k)];                                          \
            acc[0] += (float)v[0]; acc[1] += (float)v[1];                      \
            acc[2] += (float)v[2]; acc[3] += (float)v[3];                      \
        }                                                                      \
    }

    // ---- prologue: issue c0+c1 rates and y rows, stage y_s ----
    ISSUE_PH1(qA, 0)
    float v0 = y_in[(b0 + 0) * 1024 + tid];
    float v1 = y_in[(b0 + 1) * 1024 + tid];
    float v2 = y_in[(b0 + 2) * 1024 + tid];
    float v3 = y_in[(b0 + 3) * 1024 + tid];
    ISSUE_PH1(qB, 1)
    {
        half4 hy;
        hy[0] = (_Float16)v0; hy[1] = (_Float16)v1;
        hy[2] = (_Float16)v2; hy[3] = (_Float16)v3;
        y_s[tid] = hy;
    }
    LDS_BARRIER();                       // y_s ready; qA/qB in flight
    WRITE_PH1(0, qA, 0)                  // buf0 = chunk0
    LDS_BARRIER();

    // ---- steady-state regions: issue chunk g+1, sum chunk g-1, write g ----
    ISSUE_PH2(qA, 0) SUM(0, 0) WRITE_PH1(1, qB, 1) LDS_BARRIER();  // g=1
    ISSUE_PH2(qB, 1) SUM(1, 1) WRITE_PH2(0, qA, 0) LDS_BARRIER();  // g=2
    ISSUE_PH2(qA, 2) SUM(2, 0) WRITE_PH2(1, qB, 1) LDS_BARRIER();  // g=3
    ISSUE_PH2(qB, 3) SUM(3, 1) WRITE_PH2(0, qA, 2) LDS_BARRIER();  // g=4
    ISSUE_PH2(qA, 4) SUM(4, 0) WRITE_PH2(1, qB, 3) LDS_BARRIER();  // g=5
    ISSUE_PH2(qB, 5) SUM(5, 1) WRITE_PH2(0, qA, 4) LDS_BARRIER();  // g=6
    ISSUE_PH2(qA, 6) SUM(6, 0) WRITE_PH2(1, qB, 5) LDS_BARRIER();  // g=7
    ISSUE_PH2(qB, 7) SUM(7, 1) WRITE_PH2(0, qA, 6) LDS_BARRIER();  // g=8
    SUM(8, 0)        WRITE_PH2(1, qB, 7) LDS_BARRIER();            // g=9
    SUM(9, 1)

#pragma unroll
    for (int r = 0; r < 4; ++r)
        y_out[(b0 + r) * 1024 + tid] = acc[r];

#undef ISSUE_PH1
#undef ISSUE_PH2
#undef WRITE_PH1
#undef WRITE_PH2
#undef SUM
}

// ---------- Fallback (generic sizes) ------------------------------------------
template <int BLOCK>
__global__ __launch_bounds__(BLOCK) void reaction_fallback(
    const float* __restrict__ y_in, const float* __restrict__ rate_1,
    const float* __restrict__ rate_2, const int* __restrict__ inds_1r,
    const int* __restrict__ inds_1p, const int* __restrict__ inds_2r,
    const int* __restrict__ inds_2p, float* __restrict__ y_out,
    int S, int N1, int N2) {
    extern __shared__ float smem[];
    float* y_s = smem;
    float* acc = smem + S;
    const int b = blockIdx.x, tid = threadIdx.x;
    const float* yrow = y_in + (size_t)b * S;
    for (int i = tid; i < S; i += BLOCK) { y_s[i] = yrow[i]; acc[i] = 0.f; }
    __syncthreads();
    const float* r1 = rate_1 + (size_t)b * N1;
    for (int i = tid; i < N1; i += BLOCK)
        atomicAdd(&acc[inds_1p[i]], y_s[inds_1r[i]] * r1[i]);
    const float* r2 = rate_2 + (size_t)b * N2;
    for (int i = tid; i < N2; i += BLOCK)
        atomicAdd(&acc[inds_2p[i]], y_s[inds_2r[2 * i]] * y_s[inds_2r[2 * i + 1]] * r2[i]);
    __syncthreads();
    float* orow = y_out + (size_t)b * S;
    for (int i = tid; i < S; i += BLOCK) orow[i] = acc[i];
}

extern "C" void kernel_launch(void* const* d_in, const int* in_sizes, int n_in,
                              void* d_out, int out_size, void* d_ws, size_t ws_size,
                              hipStream_t stream) {
    const float* y_in    = (const float*)d_in[0];
    const float* rate_1  = (const float*)d_in[1];
    const float* rate_2  = (const float*)d_in[2];
    const int*   inds_1r = (const int*)d_in[3];
    const int*   inds_1p = (const int*)d_in[4];
    const int*   inds_2r = (const int*)d_in[5];
    const int*   inds_2p = (const int*)d_in[6];
    float*       y_out   = (float*)d_out;

    const int N1 = in_sizes[3];           // 4096
    const int N2 = in_sizes[6];           // 16384
    const int B  = in_sizes[1] / N1;      // 4096
    const int S  = in_sizes[0] / B;       // 1024

    const bool specialized = (S == 1024 && N1 == 4096 && N2 == 16384 &&
                              (B % 4) == 0 && ws_size >= (size_t)(80 * 1024));
    if (!specialized) {
        size_t smem = (size_t)2 * S * sizeof(float);
        reaction_fallback<256><<<B, 256, smem, stream>>>(
            y_in, rate_1, rate_2, inds_1r, inds_1p, inds_2r, inds_2p,
            y_out, S, N1, N2);
        return;
    }

    // Workspace:
    //   segpack : 10240 u32 [ 0K, 40K)  (10 chunks; start | n<<16)
    //   pos1    :  4096 u16 [40K, 48K)  (chunk-local swizzled positions)
    //   pos2    : 16384 u16 [48K, 80K)
    char* ws = (char*)d_ws;
    unsigned*       segpack = (unsigned*)(ws + 0);
    unsigned short* pos1    = (unsigned short*)(ws + 40 * 1024);
    unsigned short* pos2    = (unsigned short*)(ws + 48 * 1024);

    setup_kernel<<<10, 1024, 0, stream>>>(inds_1p, inds_2p, pos1, pos2, segpack);
    reaction_gather4p<<<B / 4, 1024, 0, stream>>>(y_in, rate_1, rate_2,
                                                  inds_1r, inds_2r, pos1, pos2,
                                                  segpack, y_out);
}

// Round 16
// 74.184 us; speedup vs baseline: 1.1568x; 1.1568x over previous
//
#include <hip/hip_runtime.h>

// ReactionTerm v12b (final structure): R12 (79.4us, best) + nontemporal rate
// loads. (R14 resubmit: NT loads go through clang ext_vector f32x4 — the
// builtin rejects HIP's struct-based float4.)
// R8-R13 falsified every structural lever for the residual vs the ~51us HBM
// floor (reg-dbuf: occupancy cliff; rotation/mixed-regions/LDS-width: null;
// cross-region float2 pipeline: regression). The residual is HBM read-mix
// efficiency + setup/tail. NT hints keep the 320MB stream-once rate data out
// of L2, reserving it for the index/pos streams all 1024 blocks re-read.
// Geometry: B=4096, S=1024, N1=4096, N2=16384.

typedef __attribute__((ext_vector_type(4))) _Float16 half4;
typedef __attribute__((ext_vector_type(4))) float    f32x4;

#define SWL(k) ((k) ^ (((k) >> 3) & 7))
#define NTL4(base, idx) __builtin_nontemporal_load(&((const f32x4*)(base))[idx])

// ---------- setup: 5 blocks (0: ph1; 1..4: ph2 chunk), 4096 terms each -------
__global__ __launch_bounds__(1024) void setup_kernel(
    const int* __restrict__ i1p, const int* __restrict__ i2p,
    unsigned short* __restrict__ pos1, unsigned short* __restrict__ pos2,
    unsigned* __restrict__ segpack) {
    __shared__ int h[1024];
    __shared__ int wsum[16];
    const int tid = threadIdx.x;
    const int ch  = blockIdx.x;
    const int* __restrict__ ip = (ch == 0) ? i1p : (i2p + (ch - 1) * 4096);
    unsigned short* __restrict__ pos = (ch == 0) ? pos1 : (pos2 + (ch - 1) * 4096);

    h[tid] = 0;
    __syncthreads();
    const int4 t4 = ((const int4*)ip)[tid];   // terms 4tid..4tid+3
    atomicAdd(&h[t4.x], 1);
    atomicAdd(&h[t4.y], 1);
    atomicAdd(&h[t4.z], 1);
    atomicAdd(&h[t4.w], 1);
    __syncthreads();
    const int n = h[tid];

    // 1024-wide exclusive scan: wave shfl butterfly + 16-wave combine.
    const int lane = tid & 63, w = tid >> 6;
    int v = n;
#pragma unroll
    for (int d = 1; d < 64; d <<= 1) {
        int t = __shfl_up(v, d, 64);
        if (lane >= d) v += t;
    }
    if (lane == 63) wsum[w] = v;
    __syncthreads();
    if (tid < 16) {
        int s = wsum[tid];
#pragma unroll
        for (int d = 1; d < 16; d <<= 1) {
            int t = __shfl_up(s, d, 64);
            if (tid >= d) s += t;
        }
        wsum[tid] = s;
    }
    __syncthreads();
    const int start = ((w ? wsum[w - 1] : 0) + v) - n;   // exclusive
    segpack[ch * 1024 + tid] = (unsigned)start | ((unsigned)n << 16);
    __syncthreads();
    h[tid] = start;                                      // reuse as cursor
    __syncthreads();
    const int p0 = atomicAdd(&h[t4.x], 1);
    const int p1 = atomicAdd(&h[t4.y], 1);
    const int p2 = atomicAdd(&h[t4.z], 1);
    const int p3 = atomicAdd(&h[t4.w], 1);
    ushort4 o;
    o.x = (unsigned short)SWL(p0);
    o.y = (unsigned short)SWL(p1);
    o.z = (unsigned short)SWL(p2);
    o.w = (unsigned short)SWL(p3);
    ((ushort4*)pos)[tid] = o;
}

// ---------- main: 4 rows/block (fp16 buf), 1024 threads ----------------------
__global__ __launch_bounds__(1024, 8) void reaction_gather4h(
    const float* __restrict__ y_in, const float* __restrict__ rate_1,
    const float* __restrict__ rate_2,
    const int* __restrict__ i1r, const int* __restrict__ i2r,
    const unsigned short* __restrict__ pos1, const unsigned short* __restrict__ pos2,
    const unsigned* __restrict__ segpack,
    float* __restrict__ y_out) {
    __shared__ half4 y_s[1024];     //  8 KB: 4 rows fp16
    __shared__ half4 buf[2][4096];  // 64 KB: double-buffered product chunks

    const int tid = threadIdx.x;
    const long b0 = (long)blockIdx.x * 4;
    const float* __restrict__ r1b = rate_1 + b0 * 4096;
    const float* __restrict__ r2b = rate_2 + b0 * 16384;

    float acc[4] = {0.f, 0.f, 0.f, 0.f};

    // q0..q3 = row r's rates for this thread's 4 terms (f32x4, 16B/lane, NT).
#define LOAD_PH1()                                                             \
    int4    ia = ((const int4*)i1r)[tid];                                      \
    ushort4 pp = ((const ushort4*)pos1)[tid];                                  \
    f32x4 q0 = NTL4(r1b,          tid);                                        \
    f32x4 q1 = NTL4(r1b +  4096,  tid);                                        \
    f32x4 q2 = NTL4(r1b +  8192,  tid);                                        \
    f32x4 q3 = NTL4(r1b + 12288,  tid);

#define WRITE_PH1(P)                                                           \
    {                                                                          \
        half4 yv, pr;                                                          \
        yv = y_s[ia.x];                                                        \
        pr[0] = (_Float16)((float)yv[0] * q0.x); pr[1] = (_Float16)((float)yv[1] * q1.x); \
        pr[2] = (_Float16)((float)yv[2] * q2.x); pr[3] = (_Float16)((float)yv[3] * q3.x); \
        buf[P][pp.x] = pr;                                                     \
        yv = y_s[ia.y];                                                        \
        pr[0] = (_Float16)((float)yv[0] * q0.y); pr[1] = (_Float16)((float)yv[1] * q1.y); \
        pr[2] = (_Float16)((float)yv[2] * q2.y); pr[3] = (_Float16)((float)yv[3] * q3.y); \
        buf[P][pp.y] = pr;                                                     \
        yv = y_s[ia.z];                                                        \
        pr[0] = (_Float16)((float)yv[0] * q0.z); pr[1] = (_Float16)((float)yv[1] * q1.z); \
        pr[2] = (_Float16)((float)yv[2] * q2.z); pr[3] = (_Float16)((float)yv[3] * q3.z); \
        buf[P][pp.z] = pr;                                                     \
        yv = y_s[ia.w];                                                        \
        pr[0] = (_Float16)((float)yv[0] * q0.w); pr[1] = (_Float16)((float)yv[1] * q1.w); \
        pr[2] = (_Float16)((float)yv[2] * q2.w); pr[3] = (_Float16)((float)yv[3] * q3.w); \
        buf[P][pp.w] = pr;                                                     \
    }

#define LOAD_PH2(C)                                                            \
    int4    e0 = ((const int4*)(i2r + (C) * 8192))[2 * tid];      /* t0,t1 */  \
    int4    e1 = ((const int4*)(i2r + (C) * 8192))[2 * tid + 1];  /* t2,t3 */  \
    ushort4 pp = ((const ushort4*)(pos2 + (C) * 4096))[tid];                   \
    f32x4 q0 = NTL4(r2b + (C) * 4096,          tid);                           \
    f32x4 q1 = NTL4(r2b + (C) * 4096 + 16384,  tid);                           \
    f32x4 q2 = NTL4(r2b + (C) * 4096 + 32768,  tid);                           \
    f32x4 q3 = NTL4(r2b + (C) * 4096 + 49152,  tid);

#define WRITE_PH2(P)                                                           \
    {                                                                          \
        half4 ya, yb, pr;                                                      \
        ya = y_s[e0.x]; yb = y_s[e0.y];                                        \
        pr[0] = (_Float16)((float)ya[0] * (float)yb[0] * q0.x);                \
        pr[1] = (_Float16)((float)ya[1] * (float)yb[1] * q1.x);                \
        pr[2] = (_Float16)((float)ya[2] * (float)yb[2] * q2.x);                \
        pr[3] = (_Float16)((float)ya[3] * (float)yb[3] * q3.x);                \
        buf[P][pp.x] = pr;                                                     \
        ya = y_s[e0.z]; yb = y_s[e0.w];                                        \
        pr[0] = (_Float16)((float)ya[0] * (float)yb[0] * q0.y);                \
        pr[1] = (_Float16)((float)ya[1] * (float)yb[1] * q1.y);                \
        pr[2] = (_Float16)((float)ya[2] * (float)yb[2] * q2.y);                \
        pr[3] = (_Float16)((float)ya[3] * (float)yb[3] * q3.y);                \
        buf[P][pp.y] = pr;                                                     \
        ya = y_s[e1.x]; yb = y_s[e1.y];                                        \
        pr[0] = (_Float16)((float)ya[0] * (float)yb[0] * q0.z);                \
        pr[1] = (_Float16)((float)ya[1] * (float)yb[1] * q1.z);                \
        pr[2] = (_Float16)((float)ya[2] * (float)yb[2] * q2.z);                \
        pr[3] = (_Float16)((float)ya[3] * (float)yb[3] * q3.z);                \
        buf[P][pp.z] = pr;                                                     \
        ya = y_s[e1.z]; yb = y_s[e1.w];                                        \
        pr[0] = (_Float16)((float)ya[0] * (float)yb[0] * q0.w);                \
        pr[1] = (_Float16)((float)ya[1] * (float)yb[1] * q1.w);                \
        pr[2] = (_Float16)((float)ya[2] * (float)yb[2] * q2.w);                \
        pr[3] = (_Float16)((float)ya[3] * (float)yb[3] * q3.w);                \
        buf[P][pp.w] = pr;                                                     \
    }

#define SUM(CH, P)                                                             \
    {                                                                          \
        unsigned sp = segpack[(CH) * 1024 + tid];                              \
        int s = (int)(sp & 0xffffu), n = (int)(sp >> 16);                      \
        for (int k = s; k < s + n; ++k) {                                      \
            half4 v = buf[P][SWL(k)];                                          \
            acc[0] += (float)v[0]; acc[1] += (float)v[1];                      \
            acc[2] += (float)v[2]; acc[3] += (float)v[3];                      \
        }                                                                      \
    }

#define B_ __syncthreads()

    // Prologue: issue ph1 loads, stage y rows (fp16), write products 0.
    {
        LOAD_PH1()
        half4 hy;
#pragma unroll
        for (int r = 0; r < 4; ++r)
            hy[r] = (_Float16)y_in[(b0 + r) * 1024 + tid];
        y_s[tid] = hy;
        B_;  // y_s ready
        WRITE_PH1(0)
    }
    B_;
    { LOAD_PH2(0) SUM(0, 0) WRITE_PH2(1) }  B_;
    { LOAD_PH2(1) SUM(1, 1) WRITE_PH2(0) }  B_;
    { LOAD_PH2(2) SUM(2, 0) WRITE_PH2(1) }  B_;
    { LOAD_PH2(3) SUM(3, 1) WRITE_PH2(0) }  B_;
    SUM(4, 0)

#pragma unroll
    for (int r = 0; r < 4; ++r)
        y_out[(b0 + r) * 1024 + tid] = acc[r];

#undef LOAD_PH1
#undef WRITE_PH1
#undef LOAD_PH2
#undef WRITE_PH2
#undef SUM
#undef B_
}

// ---------- Fallback (generic sizes) ------------------------------------------
template <int BLOCK>
__global__ __launch_bounds__(BLOCK) void reaction_fallback(
    const float* __restrict__ y_in, const float* __restrict__ rate_1,
    const float* __restrict__ rate_2, const int* __restrict__ inds_1r,
    const int* __restrict__ inds_1p, const int* __restrict__ inds_2r,
    const int* __restrict__ inds_2p, float* __restrict__ y_out,
    int S, int N1, int N2) {
    extern __shared__ float smem[];
    float* y_s = smem;
    float* acc = smem + S;
    const int b = blockIdx.x, tid = threadIdx.x;
    const float* yrow = y_in + (size_t)b * S;
    for (int i = tid; i < S; i += BLOCK) { y_s[i] = yrow[i]; acc[i] = 0.f; }
    __syncthreads();
    const float* r1 = rate_1 + (size_t)b * N1;
    for (int i = tid; i < N1; i += BLOCK)
        atomicAdd(&acc[inds_1p[i]], y_s[inds_1r[i]] * r1[i]);
    const float* r2 = rate_2 + (size_t)b * N2;
    for (int i = tid; i < N2; i += BLOCK)
        atomicAdd(&acc[inds_2p[i]], y_s[inds_2r[2 * i]] * y_s[inds_2r[2 * i + 1]] * r2[i]);
    __syncthreads();
    float* orow = y_out + (size_t)b * S;
    for (int i = tid; i < S; i += BLOCK) orow[i] = acc[i];
}

extern "C" void kernel_launch(void* const* d_in, const int* in_sizes, int n_in,
                              void* d_out, int out_size, void* d_ws, size_t ws_size,
                              hipStream_t stream) {
    const float* y_in    = (const float*)d_in[0];
    const float* rate_1  = (const float*)d_in[1];
    const float* rate_2  = (const float*)d_in[2];
    const int*   inds_1r = (const int*)d_in[3];
    const int*   inds_1p = (const int*)d_in[4];
    const int*   inds_2r = (const int*)d_in[5];
    const int*   inds_2p = (const int*)d_in[6];
    float*       y_out   = (float*)d_out;

    const int N1 = in_sizes[3];           // 4096
    const int N2 = in_sizes[6];           // 16384
    const int B  = in_sizes[1] / N1;      // 4096
    const int S  = in_sizes[0] / B;       // 1024

    const bool specialized = (S == 1024 && N1 == 4096 && N2 == 16384 &&
                              (B % 4) == 0 && ws_size >= (size_t)(60 * 1024));
    if (!specialized) {
        size_t smem = (size_t)2 * S * sizeof(float);
        reaction_fallback<256><<<B, 256, smem, stream>>>(
            y_in, rate_1, rate_2, inds_1r, inds_1p, inds_2r, inds_2p,
            y_out, S, N1, N2);
        return;
    }

    // Workspace:
    //   segpack : 5120 u32  [ 0K, 20K)  (ph1 + 4 ph2 chunks; start | n<<16)
    //   pos1    : 4096 u16  [20K, 28K)  (swizzled positions)
    //   pos2    : 16384 u16 [28K, 60K)  (chunk-local swizzled positions)
    char* ws = (char*)d_ws;
    unsigned*       segpack = (unsigned*)(ws + 0);
    unsigned short* pos1    = (unsigned short*)(ws + 20 * 1024);
    unsigned short* pos2    = (unsigned short*)(ws + 28 * 1024);

    setup_kernel<<<5, 1024, 0, stream>>>(inds_1p, inds_2p, pos1, pos2, segpack);
    reaction_gather4h<<<B / 4, 1024, 0, stream>>>(y_in, rate_1, rate_2,
                                                  inds_1r, inds_2r, pos1, pos2,
                                                  segpack, y_out);
}

// Round 17
// 70.538 us; speedup vs baseline: 1.2166x; 1.0517x over previous
//
#include <hip/hip_runtime.h>

// ReactionTerm v13 (final): R15 (74.2us) + nontemporal y_out stores / y_in
// loads — completes the "stream-once data bypasses L2" policy (NT rate loads
// won 5.2us in R15 by reserving L2 for the index/pos streams all 1024 blocks
// re-read). Structure frozen: R8-R13 falsified all structural levers
// (reg-dbuf: occupancy cliff; rotation/mixed-regions/LDS-width: null;
// cross-region pipeline: regression). Geometry: B=4096,S=1024,N1=4096,N2=16384.

typedef __attribute__((ext_vector_type(4))) _Float16 half4;
typedef __attribute__((ext_vector_type(4))) float    f32x4;

#define SWL(k) ((k) ^ (((k) >> 3) & 7))
#define NTL4(base, idx) __builtin_nontemporal_load(&((const f32x4*)(base))[idx])

// ---------- setup: 5 blocks (0: ph1; 1..4: ph2 chunk), 4096 terms each -------
__global__ __launch_bounds__(1024) void setup_kernel(
    const int* __restrict__ i1p, const int* __restrict__ i2p,
    unsigned short* __restrict__ pos1, unsigned short* __restrict__ pos2,
    unsigned* __restrict__ segpack) {
    __shared__ int h[1024];
    __shared__ int wsum[16];
    const int tid = threadIdx.x;
    const int ch  = blockIdx.x;
    const int* __restrict__ ip = (ch == 0) ? i1p : (i2p + (ch - 1) * 4096);
    unsigned short* __restrict__ pos = (ch == 0) ? pos1 : (pos2 + (ch - 1) * 4096);

    h[tid] = 0;
    __syncthreads();
    const int4 t4 = ((const int4*)ip)[tid];   // terms 4tid..4tid+3
    atomicAdd(&h[t4.x], 1);
    atomicAdd(&h[t4.y], 1);
    atomicAdd(&h[t4.z], 1);
    atomicAdd(&h[t4.w], 1);
    __syncthreads();
    const int n = h[tid];

    // 1024-wide exclusive scan: wave shfl butterfly + 16-wave combine.
    const int lane = tid & 63, w = tid >> 6;
    int v = n;
#pragma unroll
    for (int d = 1; d < 64; d <<= 1) {
        int t = __shfl_up(v, d, 64);
        if (lane >= d) v += t;
    }
    if (lane == 63) wsum[w] = v;
    __syncthreads();
    if (tid < 16) {
        int s = wsum[tid];
#pragma unroll
        for (int d = 1; d < 16; d <<= 1) {
            int t = __shfl_up(s, d, 64);
            if (tid >= d) s += t;
        }
        wsum[tid] = s;
    }
    __syncthreads();
    const int start = ((w ? wsum[w - 1] : 0) + v) - n;   // exclusive
    segpack[ch * 1024 + tid] = (unsigned)start | ((unsigned)n << 16);
    __syncthreads();
    h[tid] = start;                                      // reuse as cursor
    __syncthreads();
    const int p0 = atomicAdd(&h[t4.x], 1);
    const int p1 = atomicAdd(&h[t4.y], 1);
    const int p2 = atomicAdd(&h[t4.z], 1);
    const int p3 = atomicAdd(&h[t4.w], 1);
    ushort4 o;
    o.x = (unsigned short)SWL(p0);
    o.y = (unsigned short)SWL(p1);
    o.z = (unsigned short)SWL(p2);
    o.w = (unsigned short)SWL(p3);
    ((ushort4*)pos)[tid] = o;
}

// ---------- main: 4 rows/block (fp16 buf), 1024 threads ----------------------
__global__ __launch_bounds__(1024, 8) void reaction_gather4h(
    const float* __restrict__ y_in, const float* __restrict__ rate_1,
    const float* __restrict__ rate_2,
    const int* __restrict__ i1r, const int* __restrict__ i2r,
    const unsigned short* __restrict__ pos1, const unsigned short* __restrict__ pos2,
    const unsigned* __restrict__ segpack,
    float* __restrict__ y_out) {
    __shared__ half4 y_s[1024];     //  8 KB: 4 rows fp16
    __shared__ half4 buf[2][4096];  // 64 KB: double-buffered product chunks

    const int tid = threadIdx.x;
    const long b0 = (long)blockIdx.x * 4;
    const float* __restrict__ r1b = rate_1 + b0 * 4096;
    const float* __restrict__ r2b = rate_2 + b0 * 16384;

    float acc[4] = {0.f, 0.f, 0.f, 0.f};

    // q0..q3 = row r's rates for this thread's 4 terms (f32x4, 16B/lane, NT).
#define LOAD_PH1()                                                             \
    int4    ia = ((const int4*)i1r)[tid];                                      \
    ushort4 pp = ((const ushort4*)pos1)[tid];                                  \
    f32x4 q0 = NTL4(r1b,          tid);                                        \
    f32x4 q1 = NTL4(r1b +  4096,  tid);                                        \
    f32x4 q2 = NTL4(r1b +  8192,  tid);                                        \
    f32x4 q3 = NTL4(r1b + 12288,  tid);

#define WRITE_PH1(P)                                                           \
    {                                                                          \
        half4 yv, pr;                                                          \
        yv = y_s[ia.x];                                                        \
        pr[0] = (_Float16)((float)yv[0] * q0.x); pr[1] = (_Float16)((float)yv[1] * q1.x); \
        pr[2] = (_Float16)((float)yv[2] * q2.x); pr[3] = (_Float16)((float)yv[3] * q3.x); \
        buf[P][pp.x] = pr;                                                     \
        yv = y_s[ia.y];                                                        \
        pr[0] = (_Float16)((float)yv[0] * q0.y); pr[1] = (_Float16)((float)yv[1] * q1.y); \
        pr[2] = (_Float16)((float)yv[2] * q2.y); pr[3] = (_Float16)((float)yv[3] * q3.y); \
        buf[P][pp.y] = pr;                                                     \
        yv = y_s[ia.z];                                                        \
        pr[0] = (_Float16)((float)yv[0] * q0.z); pr[1] = (_Float16)((float)yv[1] * q1.z); \
        pr[2] = (_Float16)((float)yv[2] * q2.z); pr[3] = (_Float16)((float)yv[3] * q3.z); \
        buf[P][pp.z] = pr;                                                     \
        yv = y_s[ia.w];                                                        \
        pr[0] = (_Float16)((float)yv[0] * q0.w); pr[1] = (_Float16)((float)yv[1] * q1.w); \
        pr[2] = (_Float16)((float)yv[2] * q2.w); pr[3] = (_Float16)((float)yv[3] * q3.w); \
        buf[P][pp.w] = pr;                                                     \
    }

#define LOAD_PH2(C)                                                            \
    int4    e0 = ((const int4*)(i2r + (C) * 8192))[2 * tid];      /* t0,t1 */  \
    int4    e1 = ((const int4*)(i2r + (C) * 8192))[2 * tid + 1];  /* t2,t3 */  \
    ushort4 pp = ((const ushort4*)(pos2 + (C) * 4096))[tid];                   \
    f32x4 q0 = NTL4(r2b + (C) * 4096,          tid);                           \
    f32x4 q1 = NTL4(r2b + (C) * 4096 + 16384,  tid);                           \
    f32x4 q2 = NTL4(r2b + (C) * 4096 + 32768,  tid);                           \
    f32x4 q3 = NTL4(r2b + (C) * 4096 + 49152,  tid);

#define WRITE_PH2(P)                                                           \
    {                                                                          \
        half4 ya, yb, pr;                                                      \
        ya = y_s[e0.x]; yb = y_s[e0.y];                                        \
        pr[0] = (_Float16)((float)ya[0] * (float)yb[0] * q0.x);                \
        pr[1] = (_Float16)((float)ya[1] * (float)yb[1] * q1.x);                \
        pr[2] = (_Float16)((float)ya[2] * (float)yb[2] * q2.x);                \
        pr[3] = (_Float16)((float)ya[3] * (float)yb[3] * q3.x);                \
        buf[P][pp.x] = pr;                                                     \
        ya = y_s[e0.z]; yb = y_s[e0.w];                                        \
        pr[0] = (_Float16)((float)ya[0] * (float)yb[0] * q0.y);                \
        pr[1] = (_Float16)((float)ya[1] * (float)yb[1] * q1.y);                \
        pr[2] = (_Float16)((float)ya[2] * (float)yb[2] * q2.y);                \
        pr[3] = (_Float16)((float)ya[3] * (float)yb[3] * q3.y);                \
        buf[P][pp.y] = pr;                                                     \
        ya = y_s[e1.x]; yb = y_s[e1.y];                                        \
        pr[0] = (_Float16)((float)ya[0] * (float)yb[0] * q0.z);                \
        pr[1] = (_Float16)((float)ya[1] * (float)yb[1] * q1.z);                \
        pr[2] = (_Float16)((float)ya[2] * (float)yb[2] * q2.z);                \
        pr[3] = (_Float16)((float)ya[3] * (float)yb[3] * q3.z);                \
        buf[P][pp.z] = pr;                                                     \
        ya = y_s[e1.z]; yb = y_s[e1.w];                                        \
        pr[0] = (_Float16)((float)ya[0] * (float)yb[0] * q0.w);                \
        pr[1] = (_Float16)((float)ya[1] * (float)yb[1] * q1.w);                \
        pr[2] = (_Float16)((float)ya[2] * (float)yb[2] * q2.w);                \
        pr[3] = (_Float16)((float)ya[3] * (float)yb[3] * q3.w);                \
        buf[P][pp.w] = pr;                                                     \
    }

#define SUM(CH, P)                                                             \
    {                                                                          \
        unsigned sp = segpack[(CH) * 1024 + tid];                              \
        int s = (int)(sp & 0xffffu), n = (int)(sp >> 16);                      \
        for (int k = s; k < s + n; ++k) {                                      \
            half4 v = buf[P][SWL(k)];                                          \
            acc[0] += (float)v[0]; acc[1] += (float)v[1];                      \
            acc[2] += (float)v[2]; acc[3] += (float)v[3];                      \
        }                                                                      \
    }

#define B_ __syncthreads()

    // Prologue: issue ph1 loads, stage y rows (fp16, NT loads), write products 0.
    {
        LOAD_PH1()
        half4 hy;
#pragma unroll
        for (int r = 0; r < 4; ++r)
            hy[r] = (_Float16)__builtin_nontemporal_load(&y_in[(b0 + r) * 1024 + tid]);
        y_s[tid] = hy;
        B_;  // y_s ready
        WRITE_PH1(0)
    }
    B_;
    { LOAD_PH2(0) SUM(0, 0) WRITE_PH2(1) }  B_;
    { LOAD_PH2(1) SUM(1, 1) WRITE_PH2(0) }  B_;
    { LOAD_PH2(2) SUM(2, 0) WRITE_PH2(1) }  B_;
    { LOAD_PH2(3) SUM(3, 1) WRITE_PH2(0) }  B_;
    SUM(4, 0)

#pragma unroll
    for (int r = 0; r < 4; ++r)
        __builtin_nontemporal_store(acc[r], &y_out[(b0 + r) * 1024 + tid]);

#undef LOAD_PH1
#undef WRITE_PH1
#undef LOAD_PH2
#undef WRITE_PH2
#undef SUM
#undef B_
}

// ---------- Fallback (generic sizes) ------------------------------------------
template <int BLOCK>
__global__ __launch_bounds__(BLOCK) void reaction_fallback(
    const float* __restrict__ y_in, const float* __restrict__ rate_1,
    const float* __restrict__ rate_2, const int* __restrict__ inds_1r,
    const int* __restrict__ inds_1p, const int* __restrict__ inds_2r,
    const int* __restrict__ inds_2p, float* __restrict__ y_out,
    int S, int N1, int N2) {
    extern __shared__ float smem[];
    float* y_s = smem;
    float* acc = smem + S;
    const int b = blockIdx.x, tid = threadIdx.x;
    const float* yrow = y_in + (size_t)b * S;
    for (int i = tid; i < S; i += BLOCK) { y_s[i] = yrow[i]; acc[i] = 0.f; }
    __syncthreads();
    const float* r1 = rate_1 + (size_t)b * N1;
    for (int i = tid; i < N1; i += BLOCK)
        atomicAdd(&acc[inds_1p[i]], y_s[inds_1r[i]] * r1[i]);
    const float* r2 = rate_2 + (size_t)b * N2;
    for (int i = tid; i < N2; i += BLOCK)
        atomicAdd(&acc[inds_2p[i]], y_s[inds_2r[2 * i]] * y_s[inds_2r[2 * i + 1]] * r2[i]);
    __syncthreads();
    float* orow = y_out + (size_t)b * S;
    for (int i = tid; i < S; i += BLOCK) orow[i] = acc[i];
}

extern "C" void kernel_launch(void* const* d_in, const int* in_sizes, int n_in,
                              void* d_out, int out_size, void* d_ws, size_t ws_size,
                              hipStream_t stream) {
    const float* y_in    = (const float*)d_in[0];
    const float* rate_1  = (const float*)d_in[1];
    const float* rate_2  = (const float*)d_in[2];
    const int*   inds_1r = (const int*)d_in[3];
    const int*   inds_1p = (const int*)d_in[4];
    const int*   inds_2r = (const int*)d_in[5];
    const int*   inds_2p = (const int*)d_in[6];
    float*       y_out   = (float*)d_out;

    const int N1 = in_sizes[3];           // 4096
    const int N2 = in_sizes[6];           // 16384
    const int B  = in_sizes[1] / N1;      // 4096
    const int S  = in_sizes[0] / B;       // 1024

    const bool specialized = (S == 1024 && N1 == 4096 && N2 == 16384 &&
                              (B % 4) == 0 && ws_size >= (size_t)(60 * 1024));
    if (!specialized) {
        size_t smem = (size_t)2 * S * sizeof(float);
        reaction_fallback<256><<<B, 256, smem, stream>>>(
            y_in, rate_1, rate_2, inds_1r, inds_1p, inds_2r, inds_2p,
            y_out, S, N1, N2);
        return;
    }

    // Workspace:
    //   segpack : 5120 u32  [ 0K, 20K)  (ph1 + 4 ph2 chunks; start | n<<16)
    //   pos1    : 4096 u16  [20K, 28K)  (swizzled positions)
    //   pos2    : 16384 u16 [28K, 60K)  (chunk-local swizzled positions)
    char* ws = (char*)d_ws;
    unsigned*       segpack = (unsigned*)(ws + 0);
    unsigned short* pos1    = (unsigned short*)(ws + 20 * 1024);
    unsigned short* pos2    = (unsigned short*)(ws + 28 * 1024);

    setup_kernel<<<5, 1024, 0, stream>>>(inds_1p, inds_2p, pos1, pos2, segpack);
    reaction_gather4h<<<B / 4, 1024, 0, stream>>>(y_in, rate_1, rate_2,
                                                  inds_1r, inds_2r, pos1, pos2,
                                                  segpack, y_out);
}